// Round 1
// baseline (348.277 us; speedup 1.0000x reference)
//
#include <hip/hip_runtime.h>

#define NMAT 2048

__device__ __forceinline__ float wave_reduce_sum(float v) {
    v += __shfl_down(v, 32);
    v += __shfl_down(v, 16);
    v += __shfl_down(v, 8);
    v += __shfl_down(v, 4);
    v += __shfl_down(v, 2);
    v += __shfl_down(v, 1);
    return v;
}

__device__ __forceinline__ float4 f4fma(float a, float4 b, float4 c) {
    return make_float4(fmaf(a, b.x, c.x), fmaf(a, b.y, c.y),
                       fmaf(a, b.z, c.z), fmaf(a, b.w, c.w));
}
__device__ __forceinline__ float4 f4scale(float a, float4 b) {
    return make_float4(a * b.x, a * b.y, a * b.z, a * b.w);
}

// One block per row: rowsum[i], diag[i], atomic trace/totsum.
__global__ __launch_bounds__(256) void k_rows(const float* __restrict__ in,
                                              float* __restrict__ rowsum,
                                              float* __restrict__ diag,
                                              float* __restrict__ scal) {
    const int i = blockIdx.x;
    const float4* row = (const float4*)(in + (size_t)i * NMAT);
    float s = 0.f;
#pragma unroll
    for (int k = 0; k < 2; ++k) {
        float4 v = row[threadIdx.x + k * 256];
        s += (v.x + v.y) + (v.z + v.w);
    }
    s = wave_reduce_sum(s);
    __shared__ float red[4];
    const int lane = threadIdx.x & 63;
    const int wid = threadIdx.x >> 6;
    if (lane == 0) red[wid] = s;
    __syncthreads();
    if (threadIdx.x == 0) {
        float t = (red[0] + red[1]) + (red[2] + red[3]);
        rowsum[i] = t;
        atomicAdd(&scal[1], t);          // totsum
        float d = in[(size_t)i * NMAT + i];
        diag[i] = d;
        atomicAdd(&scal[0], d);          // trace
    }
}

// Column sums: grid (8 col-stripes of 256, 32 row-chunks of 64). Coalesced reads.
__global__ __launch_bounds__(256) void k_cols(const float* __restrict__ in,
                                              float* __restrict__ colsum) {
    const int j = blockIdx.x * 256 + threadIdx.x;
    const int r0 = blockIdx.y * 64;
    float s = 0.f;
#pragma unroll 8
    for (int r = 0; r < 64; ++r)
        s += in[(size_t)(r0 + r) * NMAT + j];
    atomicAdd(&colsum[j], s);
}

// Build P/Q/D tables: one thread per (i, o-quad), 8192 threads.
__global__ __launch_bounds__(256) void k_tables(const float* __restrict__ w,
                                                const float* __restrict__ rowsum,
                                                const float* __restrict__ diag,
                                                const float* __restrict__ colsum,
                                                const float* __restrict__ scal,
                                                float4* __restrict__ P4,
                                                float4* __restrict__ Q4,
                                                float4* __restrict__ D4) {
    const int idx = blockIdx.x * 256 + threadIdx.x;   // i*4 + og
    const int i = idx >> 2;
    const int og = idx & 3;
    const float di = diag[i], rs = rowsum[i], cs = colsum[i];
    const float tr = scal[0], ts = scal[1];
    const float4* W = (const float4*)w;               // W[k*4 + og] = w[k][og*4 .. og*4+3]
    float4 P = f4scale(di, W[8 * 4 + og]);
    P = f4fma(rs, W[9 * 4 + og], P);
    P = f4fma(cs, W[10 * 4 + og], P);
    P = f4fma(tr, W[13 * 4 + og], P);
    P = f4fma(ts, W[14 * 4 + og], P);
    float4 Q = f4scale(di, W[5 * 4 + og]);
    Q = f4fma(rs, W[6 * 4 + og], Q);
    Q = f4fma(cs, W[7 * 4 + og], Q);
    float4 D = f4scale(di, W[0 * 4 + og]);
    D = f4fma(rs, W[1 * 4 + og], D);
    D = f4fma(cs, W[2 * 4 + og], D);
    D = f4fma(tr, W[3 * 4 + og], D);
    D = f4fma(ts, W[4 * 4 + og], D);
    P4[idx] = P;
    Q4[idx] = Q;
    D4[idx] = D;
}

// Main: 32x32 (i,j) tile per block, 256 threads. Lane owns fixed (tj, og);
// loops i over the tile. float4 stores are exactly lane-contiguous.
__global__ __launch_bounds__(256) void k_main(const float* __restrict__ in,
                                              const float* __restrict__ w,
                                              const float4* __restrict__ P4,
                                              const float4* __restrict__ Q4,
                                              const float4* __restrict__ D4,
                                              float4* __restrict__ out4) {
    const int t = threadIdx.x;
    const int og = t & 3;
    const int tj = (t >> 2) & 31;
    const int half = t >> 7;                 // 0 or 1 -> even/odd i within tile
    const int j = blockIdx.x * 32 + tj;
    const int i0 = blockIdx.y * 32;
    const float4* W = (const float4*)w;
    const float4 w11v = W[11 * 4 + og];
    const float4 w12v = W[12 * 4 + og];
    const float4 q = Q4[j * 4 + og];
    const size_t jrow = (size_t)j * NMAT;
#pragma unroll 4
    for (int it = 0; it < 16; ++it) {
        const int i = i0 + half + 2 * it;
        const float a = in[(size_t)i * NMAT + j];   // direct element
        const float at = in[jrow + i];              // transposed element
        const float4 p = P4[i * 4 + og];
        float4 r;
        r.x = fmaf(a, w12v.x, fmaf(at, w11v.x, p.x + q.x));
        r.y = fmaf(a, w12v.y, fmaf(at, w11v.y, p.y + q.y));
        r.z = fmaf(a, w12v.z, fmaf(at, w11v.z, p.z + q.z));
        r.w = fmaf(a, w12v.w, fmaf(at, w11v.w, p.w + q.w));
        if (i == j) {
            const float4 dd = D4[i * 4 + og];
            r.x += dd.x; r.y += dd.y; r.z += dd.z; r.w += dd.w;
        }
        out4[((size_t)i * NMAT + j) * 4 + og] = r;
    }
}

extern "C" void kernel_launch(void* const* d_in, const int* in_sizes, int n_in,
                              void* d_out, int out_size, void* d_ws, size_t ws_size,
                              hipStream_t stream) {
    const float* in = (const float*)d_in[0];   // [2048, 2048] f32
    const float* w = (const float*)d_in[1];    // [15, 16] f32
    float* ws = (float*)d_ws;

    // Workspace layout (floats):
    //   [0,2048)      colsum   (atomic-accumulated; must be zeroed)
    //   [2048,2050)   scal: trace, totsum (atomic; must be zeroed)
    //   [2056,4104)   rowsum
    //   [4104,6152)   diag
    //   [6152,...)    P (2048*16), Q (2048*16), D (2048*16)  -- 16B aligned
    float* colsum = ws;
    float* scal = ws + 2048;
    float* rowsum = ws + 2056;
    float* diag = ws + 4104;
    float4* P4 = (float4*)(ws + 6152);
    float4* Q4 = (float4*)(ws + 6152 + 32768);
    float4* D4 = (float4*)(ws + 6152 + 65536);

    hipMemsetAsync(d_ws, 0, 2050 * sizeof(float), stream);
    k_rows<<<2048, 256, 0, stream>>>(in, rowsum, diag, scal);
    k_cols<<<dim3(8, 32), 256, 0, stream>>>(in, colsum);
    k_tables<<<32, 256, 0, stream>>>(w, rowsum, diag, colsum, scal, P4, Q4, D4);
    k_main<<<dim3(64, 64), 256, 0, stream>>>(in, w, P4, Q4, D4, (float4*)d_out);
}